// Round 4
// baseline (3710.373 us; speedup 1.0000x reference)
//
#include <hip/hip_runtime.h>

#define T_IN   24
#define NB     8192
#define HD     512
#define T_OUT  12
#define ROWS   32
#define NBLK   (NB / ROWS)   // 256 blocks = 1 per CU

typedef float  f32x4  __attribute__((ext_vector_type(4)));
typedef short  bf16x8 __attribute__((ext_vector_type(8)));

__device__ __forceinline__ unsigned short f2bf(float f){
  unsigned u = __float_as_uint(f);
  u += 0x7fffu + ((u >> 16) & 1u);          // round-to-nearest-even
  return (unsigned short)(u >> 16);
}
__device__ __forceinline__ float bf2f(unsigned short h){
  return __uint_as_float(((unsigned)h) << 16);
}

// XOR-swizzled f32 index into the [ROWS][512] hidden/h2 LDS tile
// (spreads the 2KB row stride across banks for the GEMM A-frag reads)
__device__ __forceinline__ int swz(int r, int c){
  return (r << 9) + ((((c >> 3) ^ (r & 7)) << 3) | (c & 7));
}

// ---------------- W_hh -> bf16 hi/lo split (once per call) ----------------
__global__ __launch_bounds__(256) void conv_whh(const float* __restrict__ W,
                                                unsigned short* __restrict__ hi,
                                                unsigned short* __restrict__ lo){
  int idx = blockIdx.x * 256 + threadIdx.x;
  float v = W[idx];
  unsigned short h = f2bf(v);
  hi[idx] = h;
  lo[idx] = f2bf(v - bf2f(h));
}

// ---------------- persistent fused decoder: all 12 steps in one kernel ----------------
// Block owns 32 batch rows. Per step: online-softmax attention (single enc pass,
// f32 logits — precision-critical), split-bf16 MFMA GEMM vs W_hh (B-frags straight
// from L2), fused GRU gates, output dot. hidden/h2/last/ctxdot never touch HBM.
__global__ __launch_bounds__(512, 2) void decoder(
    const float* __restrict__ enc,       // f32 [t][b][h]
    const float* __restrict__ ehid,      // f32 [b][h]
    const float* __restrict__ last0,     // f32 [b][4]
    const float* __restrict__ pe,        // f32 [12][4]
    const float* __restrict__ W_ih,      // f32 [1536][8]
    const float* __restrict__ b_ih,      // f32 [1536]
    const float* __restrict__ b_hh,      // f32 [1536]
    const float* __restrict__ Wlin,      // f32 [1024]
    const float* __restrict__ blin,      // f32 [1]
    const unsigned short* __restrict__ Whi,  // bf16 [1536][512]
    const unsigned short* __restrict__ Wlo,
    float* __restrict__ outp)            // f32 [b][12]
{
  __shared__ float hid_s[ROWS * HD];     // 64 KB, swizzled; hidden -> h2 -> hidden'
  __shared__ float last_s[ROWS][4];
  __shared__ float ctxd_s[ROWS];

  const int tid = threadIdx.x;
  const int l   = tid & 63;
  const int w   = tid >> 6;        // wave 0..7
  const int g   = l >> 4;          // 16-lane group 0..3 (= GEMM k-chunk / C-row group)
  const int i   = l & 15;          // lane-in-group (= GEMM frag row/col)
  const int rl  = w * 4 + g;       // attn row 0..31
  const int rg  = blockIdx.x * ROWS + rl;
  const int c0  = i * 32;          // attn-owned h-columns [c0, c0+32)

  // ---- init: hidden <- encoder_hid, last <- last_init ----
  {
    const float* hb = ehid + (size_t)rg * HD + c0;
    #pragma unroll
    for (int k8 = 0; k8 < 4; k8++){
      f32x4 a = *(const f32x4*)(hb + k8 * 8);
      f32x4 b = *(const f32x4*)(hb + k8 * 8 + 4);
      int o = swz(rl, c0 + k8 * 8);
      *(f32x4*)(hid_s + o)     = a;
      *(f32x4*)(hid_s + o + 4) = b;
    }
    if (i == 0)
      *(float4*)(&last_s[rl][0]) = *(const float4*)(last0 + (size_t)rg * 4);
  }
  __syncthreads();

  const size_t tstride = (size_t)NB * HD;
  const float* ebase = enc + (size_t)rg * HD + c0;

  for (int s = 0; s < T_OUT; s++){
    // ================= A. attention (online softmax over t) =================
    float hidr[32];
    #pragma unroll
    for (int k8 = 0; k8 < 4; k8++){
      int o = swz(rl, c0 + k8 * 8);
      *(f32x4*)(hidr + k8 * 8)     = *(const f32x4*)(hid_s + o);
      *(f32x4*)(hidr + k8 * 8 + 4) = *(const f32x4*)(hid_s + o + 4);
    }

    float m = -3.0e38f, dsum = 0.f;
    float ctx[32];
    #pragma unroll
    for (int c = 0; c < 32; c++) ctx[c] = 0.f;

    auto online = [&](float (&E)[32]){
      float p = 0.f;
      #pragma unroll
      for (int c = 0; c < 32; c++) p += E[c] * hidr[c];
      p += __shfl_xor(p, 1); p += __shfl_xor(p, 2);
      p += __shfl_xor(p, 4); p += __shfl_xor(p, 8);   // 16-lane row dot
      float mn = fmaxf(m, p);
      float al = exp2f((m - mn) * 1.44269504f);
      float ph = exp2f((p - mn) * 1.44269504f);
      dsum = dsum * al + ph;
      #pragma unroll
      for (int c = 0; c < 32; c++) ctx[c] = ctx[c] * al + ph * E[c];
      m = mn;
    };

    float eA[32], eB[32];
    #pragma unroll
    for (int k = 0; k < 8; k++)
      *(f32x4*)(eA + k * 4) = *(const f32x4*)(ebase + k * 4);   // t = 0

    for (int t = 0; t < T_IN; t += 2){
      const float* p1 = ebase + (size_t)(t + 1) * tstride;
      #pragma unroll
      for (int k = 0; k < 8; k++)
        *(f32x4*)(eB + k * 4) = *(const f32x4*)(p1 + k * 4);
      online(eA);
      int t2 = (t + 2 < T_IN) ? t + 2 : 0;                      // clamp (dummy)
      const float* p2 = ebase + (size_t)t2 * tstride;
      #pragma unroll
      for (int k = 0; k < 8; k++)
        *(f32x4*)(eA + k * 4) = *(const f32x4*)(p2 + k * 4);
      online(eB);
    }

    // normalize context, build h2 = hidden + ctx, ctx part of out-dot
    float inv = 1.f / dsum;
    float cdot = 0.f;
    #pragma unroll
    for (int k8 = 0; k8 < 4; k8++){
      f32x4 wv0 = *(const f32x4*)(Wlin + HD + c0 + k8 * 8);
      f32x4 wv1 = *(const f32x4*)(Wlin + HD + c0 + k8 * 8 + 4);
      #pragma unroll
      for (int e = 0; e < 4; e++){
        float cv0 = ctx[k8 * 8 + e] * inv;
        float cv1 = ctx[k8 * 8 + 4 + e] * inv;
        cdot += cv0 * wv0[e] + cv1 * wv1[e];
        hidr[k8 * 8 + e]     += cv0;
        hidr[k8 * 8 + 4 + e] += cv1;
      }
    }
    cdot += __shfl_xor(cdot, 1); cdot += __shfl_xor(cdot, 2);
    cdot += __shfl_xor(cdot, 4); cdot += __shfl_xor(cdot, 8);
    if (i == 0) ctxd_s[rl] = cdot + blin[0];

    #pragma unroll
    for (int k8 = 0; k8 < 4; k8++){
      int o = swz(rl, c0 + k8 * 8);
      *(f32x4*)(hid_s + o)     = *(const f32x4*)(hidr + k8 * 8);
      *(f32x4*)(hid_s + o + 4) = *(const f32x4*)(hidr + k8 * 8 + 4);
    }
    __syncthreads();   // bar1: h2 visible to all

    // ================= C. GEMM k-sweep (gh = h2 @ W_hh^T, split bf16) =================
    // wave w owns j-tiles {w, w+8, w+16, w+24} x 3 gates x 2 M-tiles
    f32x4 acc[4][3][2];
    #pragma unroll
    for (int a = 0; a < 4; a++)
      #pragma unroll
      for (int b = 0; b < 3; b++)
        #pragma unroll
        for (int c = 0; c < 2; c++)
          acc[a][b][c] = (f32x4){0.f, 0.f, 0.f, 0.f};

    #pragma unroll 4
    for (int kt = 0; kt < 16; kt++){
      bf16x8 ah[2], al8[2];
      #pragma unroll
      for (int mt = 0; mt < 2; mt++){
        int row = mt * 16 + i;
        int o = swz(row, kt * 32 + g * 8);
        f32x4 a0 = *(const f32x4*)(hid_s + o);
        f32x4 a1 = *(const f32x4*)(hid_s + o + 4);
        #pragma unroll
        for (int e = 0; e < 8; e++){
          float v = (e < 4) ? a0[e] : a1[e - 4];
          unsigned short hb = f2bf(v);
          ah[mt][e]  = (short)hb;
          al8[mt][e] = (short)f2bf(v - bf2f(hb));
        }
      }
      #pragma unroll
      for (int mjt = 0; mjt < 4; mjt++){
        int jt = w + 8 * mjt;
        #pragma unroll
        for (int gg = 0; gg < 3; gg++){
          size_t boff = (size_t)(gg * 512 + jt * 16 + i) * HD + kt * 32 + g * 8;
          bf16x8 bh = *(const bf16x8*)(Whi + boff);
          bf16x8 bl = *(const bf16x8*)(Wlo + boff);
          #pragma unroll
          for (int mt = 0; mt < 2; mt++){
            acc[mjt][gg][mt] = __builtin_amdgcn_mfma_f32_16x16x32_bf16(ah[mt],  bh, acc[mjt][gg][mt], 0, 0, 0);
            acc[mjt][gg][mt] = __builtin_amdgcn_mfma_f32_16x16x32_bf16(al8[mt], bh, acc[mjt][gg][mt], 0, 0, 0);
            acc[mjt][gg][mt] = __builtin_amdgcn_mfma_f32_16x16x32_bf16(ah[mt],  bl, acc[mjt][gg][mt], 0, 0, 0);
          }
        }
      }
    }
    __syncthreads();   // bar2: all h2 reads done before hidden overwrite

    // ================= E. fused GRU epilogue =================
    const float pe0 = pe[s * 4 + 0], pe1 = pe[s * 4 + 1],
                pe2 = pe[s * 4 + 2], pe3 = pe[s * 4 + 3];
    #pragma unroll
    for (int mjt = 0; mjt < 4; mjt++){
      int j = (w + 8 * mjt) * 16 + i;
      const float* wrp = W_ih + (size_t)j * 8;
      const float* wzp = W_ih + (size_t)(512 + j) * 8;
      const float* wnp = W_ih + (size_t)(1024 + j) * 8;
      float4 wr0 = *(const float4*)wrp, wr1 = *(const float4*)(wrp + 4);
      float4 wz0 = *(const float4*)wzp, wz1 = *(const float4*)(wzp + 4);
      float4 wn0 = *(const float4*)wnp, wn1 = *(const float4*)(wnp + 4);
      float cr = pe0*wr1.x + pe1*wr1.y + pe2*wr1.z + pe3*wr1.w + b_ih[j]        + b_hh[j];
      float cz = pe0*wz1.x + pe1*wz1.y + pe2*wz1.z + pe3*wz1.w + b_ih[512 + j]  + b_hh[512 + j];
      float cn = pe0*wn1.x + pe1*wn1.y + pe2*wn1.z + pe3*wn1.w + b_ih[1024 + j];
      const float bhn = b_hh[1024 + j];
      #pragma unroll
      for (int mt = 0; mt < 2; mt++){
        #pragma unroll
        for (int q = 0; q < 4; q++){
          int row = mt * 16 + g * 4 + q;       // C-frag row
          float4 x = *(const float4*)(&last_s[row][0]);
          float gr = x.x*wr0.x + x.y*wr0.y + x.z*wr0.z + x.w*wr0.w + cr + acc[mjt][0][mt][q];
          float gz = x.x*wz0.x + x.y*wz0.y + x.z*wz0.z + x.w*wz0.w + cz + acc[mjt][1][mt][q];
          float gn = x.x*wn0.x + x.y*wn0.y + x.z*wn0.z + x.w*wn0.w + cn;
          float r = 1.f / (1.f + exp2f(-1.44269504f * gr));
          float z = 1.f / (1.f + exp2f(-1.44269504f * gz));
          float nn = gn + r * (acc[mjt][2][mt][q] + bhn);
          float th = 1.f - 2.f / (1.f + exp2f(2.88539008f * nn));   // tanh
          int ho = swz(row, j);
          float h = hid_s[ho];                 // h2 (owner-only read)
          hid_s[ho] = (1.f - z) * th + z * h;  // hidden' (owner-only write)
        }
      }
    }
    __syncthreads();   // bar3: hidden' visible

    // ================= G. output dot + last-ring update =================
    float pdot = 0.f;
    #pragma unroll
    for (int k8 = 0; k8 < 4; k8++){
      int o = swz(rl, c0 + k8 * 8);
      f32x4 h0 = *(const f32x4*)(hid_s + o);
      f32x4 h1 = *(const f32x4*)(hid_s + o + 4);
      f32x4 w0 = *(const f32x4*)(Wlin + c0 + k8 * 8);
      f32x4 w1 = *(const f32x4*)(Wlin + c0 + k8 * 8 + 4);
      #pragma unroll
      for (int e = 0; e < 4; e++) pdot += h0[e] * w0[e] + h1[e] * w1[e];
    }
    pdot += __shfl_xor(pdot, 1); pdot += __shfl_xor(pdot, 2);
    pdot += __shfl_xor(pdot, 4); pdot += __shfl_xor(pdot, 8);
    if (i == 0){
      float val = pdot + ctxd_s[rl];
      outp[(size_t)rg * T_OUT + s] = val;
      float4 old = *(float4*)(&last_s[rl][0]);
      last_s[rl][0] = val;   last_s[rl][1] = old.x;
      last_s[rl][2] = old.y; last_s[rl][3] = old.z;
    }
    // no barrier needed: every LDS slot touched below bar3 is owner-read/owner-write,
    // and the next step's cross-thread readers sit behind bar1/bar2.
  }
}

extern "C" void kernel_launch(void* const* d_in, const int* in_sizes, int n_in,
                              void* d_out, int out_size, void* d_ws, size_t ws_size,
                              hipStream_t stream){
  (void)in_sizes; (void)n_in; (void)out_size; (void)ws_size;
  const float* enc   = (const float*)d_in[0];
  const float* ehid  = (const float*)d_in[1];
  const float* last0 = (const float*)d_in[2];
  const float* pe    = (const float*)d_in[3];
  const float* W_ih  = (const float*)d_in[4];
  const float* W_hh  = (const float*)d_in[5];
  const float* b_ih  = (const float*)d_in[6];
  const float* b_hh  = (const float*)d_in[7];
  const float* W_lin = (const float*)d_in[8];
  const float* b_lin = (const float*)d_in[9];
  float* outp = (float*)d_out;

  char* ws = (char*)d_ws;
  unsigned short* whh_hi = (unsigned short*)ws;
  unsigned short* whh_lo = whh_hi + (size_t)1536 * 512;

  conv_whh<<<3072, 256, 0, stream>>>(W_hh, whh_hi, whh_lo);
  decoder<<<NBLK, 512, 0, stream>>>(enc, ehid, last0, pe, W_ih, b_ih, b_hh,
                                    W_lin, b_lin, whh_hi, whh_lo, outp);
}

// Round 5
// 3645.575 us; speedup vs baseline: 1.0178x; 1.0178x over previous
//
#include <hip/hip_runtime.h>

#define T_IN   24
#define NB     8192
#define HD     512
#define T_OUT  12
#define ROWS   32
#define NBLK   (NB / ROWS)   // 256 blocks = 1 per CU

typedef float  f32x4  __attribute__((ext_vector_type(4)));
typedef short  bf16x8 __attribute__((ext_vector_type(8)));

__device__ __forceinline__ unsigned short f2bf(float f){
  unsigned u = __float_as_uint(f);
  u += 0x7fffu + ((u >> 16) & 1u);          // round-to-nearest-even
  return (unsigned short)(u >> 16);
}
__device__ __forceinline__ float bf2f(unsigned short h){
  return __uint_as_float(((unsigned)h) << 16);
}

// XOR-swizzled f32 index into the [ROWS][512] hidden/h2 LDS tile.
// sch = ch ^ (r&7) ^ ((ch>>2)&3): spreads BOTH the GEMM A-frag pattern
// (r varies, ch fixed) AND the attn pattern (r fixed, ch varies by 4*li)
// across 4 bank-groups (the ds_read_b128 maximum). Bijective per row.
__device__ __forceinline__ int swz(int r, int c){
  int ch  = c >> 3;
  int sch = ch ^ (r & 7) ^ ((ch >> 2) & 3);
  return (r << 9) + (sch << 3) + (c & 7);
}

// ---- W_hh -> bf16 hi/lo split, repacked k-chunk-major: [kt][j][32] ----
// (GEMM B-frag loads become fully-coalesced 1KB wave reads from L2)
__global__ __launch_bounds__(256) void conv_whh(const float* __restrict__ W,
                                                unsigned short* __restrict__ hi,
                                                unsigned short* __restrict__ lo){
  int idx = blockIdx.x * 256 + threadIdx.x;   // 3072 blocks x 256 = 1536*512
  int j = idx >> 9, k = idx & 511;
  float v = W[idx];
  unsigned short h = f2bf(v);
  int o = ((k >> 5) * 1536 + j) * 32 + (k & 31);
  hi[o] = h;
  lo[o] = f2bf(v - bf2f(h));
}

// ---------------- persistent fused decoder: all 12 steps in one kernel ----------------
// Block owns 32 batch rows (1 block/CU). Per step: online-softmax attention
// (f32 logits — precision-critical), split-bf16 MFMA GEMM vs repacked W_hh
// (B straight from L2), fused GRU gates, output dot. All cross-step state in LDS.
__global__ __launch_bounds__(512, 2) void decoder(
    const float* __restrict__ enc,       // f32 [t][b][h]
    const float* __restrict__ ehid,      // f32 [b][h]
    const float* __restrict__ last0,     // f32 [b][4]
    const float* __restrict__ pe,        // f32 [12][4]
    const float* __restrict__ W_ih,      // f32 [1536][8]
    const float* __restrict__ b_ih,      // f32 [1536]
    const float* __restrict__ b_hh,      // f32 [1536]
    const float* __restrict__ Wlin,      // f32 [1024]
    const float* __restrict__ blin,      // f32 [1]
    const unsigned short* __restrict__ Whi,  // bf16 [16][1536][32] k-chunk-major
    const unsigned short* __restrict__ Wlo,
    float* __restrict__ outp)            // f32 [b][12]
{
  __shared__ float hid_s[ROWS * HD];     // 64 KB swizzled; hidden -> h2 -> hidden'
  __shared__ float last_s[ROWS][4];
  __shared__ float ctxd_s[ROWS];

  const int tid = threadIdx.x;
  const int l   = tid & 63;
  const int w   = tid >> 6;        // wave 0..7
  const int g   = l >> 4;          // 16-lane group 0..3 (= GEMM k-chunk / C-row group)
  const int li  = l & 15;          // lane-in-group
  const int rl  = w * 4 + g;       // attn row 0..31
  const int rg  = blockIdx.x * ROWS + rl;
  const int cb  = li * 4;          // owned cols: cb + 64*q, q=0..7 (interleaved)

  // ---- init: hidden <- encoder_hid, last <- last_init ----
  {
    const float* hb = ehid + (size_t)rg * HD + cb;
    #pragma unroll
    for (int q = 0; q < 8; q++)
      *(f32x4*)(hid_s + swz(rl, cb + q * 64)) = *(const f32x4*)(hb + q * 64);
    if (li == 0)
      *(float4*)(&last_s[rl][0]) = *(const float4*)(last0 + (size_t)rg * 4);
  }
  __syncthreads();

  const size_t tstride = (size_t)NB * HD;
  const float* ebase = enc + (size_t)rg * HD + cb;

  for (int s = 0; s < T_OUT; s++){
    // ================= A. attention (online softmax over t) =================
    f32x4 hidr[8], ctx[8];
    #pragma unroll
    for (int q = 0; q < 8; q++){
      hidr[q] = *(const f32x4*)(hid_s + swz(rl, cb + q * 64));
      ctx[q]  = (f32x4){0.f, 0.f, 0.f, 0.f};
    }
    float m = -3.0e38f, dsum = 0.f;

    f32x4 eA[8], eB[8], eC[8];
    auto loadE = [&](f32x4 (&E)[8], int tt){
      const float* pp = ebase + (size_t)tt * tstride;
      #pragma unroll
      for (int q = 0; q < 8; q++) E[q] = *(const f32x4*)(pp + q * 64);
    };
    auto online = [&](const f32x4 (&E)[8]){
      float p = 0.f;
      #pragma unroll
      for (int q = 0; q < 8; q++)
        #pragma unroll
        for (int e = 0; e < 4; e++) p += E[q][e] * hidr[q][e];
      p += __shfl_xor(p, 1); p += __shfl_xor(p, 2);
      p += __shfl_xor(p, 4); p += __shfl_xor(p, 8);   // 16-lane row dot
      float mn = fmaxf(m, p);
      float al = exp2f((m - mn) * 1.44269504f);
      float ph = exp2f((p - mn) * 1.44269504f);
      dsum = dsum * al + ph;
      #pragma unroll
      for (int q = 0; q < 8; q++) ctx[q] = ctx[q] * al + E[q] * ph;
      m = mn;
    };

    loadE(eA, 0); loadE(eB, 1);
    for (int t = 0; t < 21; t += 3){        // 3-deep ping-pong, no dummy loads
      loadE(eC, t + 2); online(eA);
      loadE(eA, t + 3); online(eB);
      loadE(eB, t + 4); online(eC);
    }
    loadE(eC, 23); online(eA); online(eB); online(eC);

    // normalize context, h2 = hidden + ctx, ctx part of out-dot
    float inv  = 1.f / dsum;
    float cdot = 0.f;
    #pragma unroll
    for (int q = 0; q < 8; q++){
      f32x4 wv = *(const f32x4*)(Wlin + HD + cb + q * 64);
      f32x4 cv = ctx[q] * inv;
      #pragma unroll
      for (int e = 0; e < 4; e++) cdot += cv[e] * wv[e];
      hidr[q] += cv;
    }
    cdot += __shfl_xor(cdot, 1); cdot += __shfl_xor(cdot, 2);
    cdot += __shfl_xor(cdot, 4); cdot += __shfl_xor(cdot, 8);
    if (li == 0) ctxd_s[rl] = cdot + blin[0];

    #pragma unroll
    for (int q = 0; q < 8; q++)
      *(f32x4*)(hid_s + swz(rl, cb + q * 64)) = hidr[q];
    __syncthreads();   // bar1: h2 visible to all

    // ================= C. GEMM k-sweep (gh = h2 @ W_hh^T, split bf16) =================
    // wave w owns j-tiles {w, w+8, w+16, w+24} x 3 gates x 2 M-tiles
    f32x4 acc[4][3][2];
    #pragma unroll
    for (int a = 0; a < 4; a++)
      #pragma unroll
      for (int b = 0; b < 3; b++)
        #pragma unroll
        for (int c = 0; c < 2; c++)
          acc[a][b][c] = (f32x4){0.f, 0.f, 0.f, 0.f};

    #pragma unroll 4
    for (int kt = 0; kt < 16; kt++){
      bf16x8 ah[2], al8[2];
      #pragma unroll
      for (int mt = 0; mt < 2; mt++){
        int row = mt * 16 + li;
        int o = swz(row, kt * 32 + g * 8);
        f32x4 a0 = *(const f32x4*)(hid_s + o);
        f32x4 a1 = *(const f32x4*)(hid_s + o + 4);
        #pragma unroll
        for (int e = 0; e < 4; e++){
          unsigned short hb0 = f2bf(a0[e]);
          unsigned short hb1 = f2bf(a1[e]);
          ah[mt][e]      = (short)hb0;
          ah[mt][e + 4]  = (short)hb1;
          al8[mt][e]     = (short)f2bf(a0[e] - bf2f(hb0));
          al8[mt][e + 4] = (short)f2bf(a1[e] - bf2f(hb1));
        }
      }
      #pragma unroll
      for (int mjt = 0; mjt < 4; mjt++){
        int jt = w + 8 * mjt;
        #pragma unroll
        for (int gg = 0; gg < 3; gg++){
          size_t boff = ((size_t)kt * 1536 + gg * 512 + jt * 16 + li) * 32 + g * 8;
          bf16x8 bh = *(const bf16x8*)(Whi + boff);
          bf16x8 bl = *(const bf16x8*)(Wlo + boff);
          #pragma unroll
          for (int mt = 0; mt < 2; mt++){
            acc[mjt][gg][mt] = __builtin_amdgcn_mfma_f32_16x16x32_bf16(ah[mt],  bh, acc[mjt][gg][mt], 0, 0, 0);
            acc[mjt][gg][mt] = __builtin_amdgcn_mfma_f32_16x16x32_bf16(al8[mt], bh, acc[mjt][gg][mt], 0, 0, 0);
            acc[mjt][gg][mt] = __builtin_amdgcn_mfma_f32_16x16x32_bf16(ah[mt],  bl, acc[mjt][gg][mt], 0, 0, 0);
          }
        }
      }
    }
    __syncthreads();   // bar2: all h2 reads done before hidden overwrite

    // ================= E. fused GRU epilogue =================
    const float pe0 = pe[s * 4 + 0], pe1 = pe[s * 4 + 1],
                pe2 = pe[s * 4 + 2], pe3 = pe[s * 4 + 3];
    #pragma unroll
    for (int mjt = 0; mjt < 4; mjt++){
      int j = (w + 8 * mjt) * 16 + li;
      const float* wrp = W_ih + (size_t)j * 8;
      const float* wzp = W_ih + (size_t)(512 + j) * 8;
      const float* wnp = W_ih + (size_t)(1024 + j) * 8;
      float4 wr0 = *(const float4*)wrp, wr1 = *(const float4*)(wrp + 4);
      float4 wz0 = *(const float4*)wzp, wz1 = *(const float4*)(wzp + 4);
      float4 wn0 = *(const float4*)wnp, wn1 = *(const float4*)(wnp + 4);
      float cr = pe0*wr1.x + pe1*wr1.y + pe2*wr1.z + pe3*wr1.w + b_ih[j]        + b_hh[j];
      float cz = pe0*wz1.x + pe1*wz1.y + pe2*wz1.z + pe3*wz1.w + b_ih[512 + j]  + b_hh[512 + j];
      float cn = pe0*wn1.x + pe1*wn1.y + pe2*wn1.z + pe3*wn1.w + b_ih[1024 + j];
      const float bhn = b_hh[1024 + j];
      #pragma unroll
      for (int mt = 0; mt < 2; mt++){
        #pragma unroll
        for (int q = 0; q < 4; q++){
          int row = mt * 16 + g * 4 + q;       // C-frag row
          float4 x = *(const float4*)(&last_s[row][0]);
          float gr = x.x*wr0.x + x.y*wr0.y + x.z*wr0.z + x.w*wr0.w + cr + acc[mjt][0][mt][q];
          float gz = x.x*wz0.x + x.y*wz0.y + x.z*wz0.z + x.w*wz0.w + cz + acc[mjt][1][mt][q];
          float gn = x.x*wn0.x + x.y*wn0.y + x.z*wn0.z + x.w*wn0.w + cn;
          float r = 1.f / (1.f + exp2f(-1.44269504f * gr));
          float z = 1.f / (1.f + exp2f(-1.44269504f * gz));
          float nn = gn + r * (acc[mjt][2][mt][q] + bhn);
          float th = 1.f - 2.f / (1.f + exp2f(2.88539008f * nn));   // tanh
          int ho = swz(row, j);
          float h = hid_s[ho];                 // h2
          hid_s[ho] = (1.f - z) * th + z * h;  // hidden'
        }
      }
    }
    __syncthreads();   // bar3: hidden' visible

    // ================= G. output dot + last-ring update =================
    float pdot = 0.f;
    #pragma unroll
    for (int q = 0; q < 8; q++){
      f32x4 hv = *(const f32x4*)(hid_s + swz(rl, cb + q * 64));
      f32x4 wv = *(const f32x4*)(Wlin + cb + q * 64);
      #pragma unroll
      for (int e = 0; e < 4; e++) pdot += hv[e] * wv[e];
    }
    pdot += __shfl_xor(pdot, 1); pdot += __shfl_xor(pdot, 2);
    pdot += __shfl_xor(pdot, 4); pdot += __shfl_xor(pdot, 8);
    if (li == 0){
      float val = pdot + ctxd_s[rl];
      outp[(size_t)rg * T_OUT + s] = val;
      float4 old = *(float4*)(&last_s[rl][0]);
      last_s[rl][0] = val;   last_s[rl][1] = old.x;
      last_s[rl][2] = old.y; last_s[rl][3] = old.z;
    }
    // no barrier needed before next step: hid_s/last_s accesses below bar3 are
    // owner-only or separated by next step's bar1/bar2 (see round-4 analysis).
  }
}

extern "C" void kernel_launch(void* const* d_in, const int* in_sizes, int n_in,
                              void* d_out, int out_size, void* d_ws, size_t ws_size,
                              hipStream_t stream){
  (void)in_sizes; (void)n_in; (void)out_size; (void)ws_size;
  const float* enc   = (const float*)d_in[0];
  const float* ehid  = (const float*)d_in[1];
  const float* last0 = (const float*)d_in[2];
  const float* pe    = (const float*)d_in[3];
  const float* W_ih  = (const float*)d_in[4];
  const float* W_hh  = (const float*)d_in[5];
  const float* b_ih  = (const float*)d_in[6];
  const float* b_hh  = (const float*)d_in[7];
  const float* W_lin = (const float*)d_in[8];
  const float* b_lin = (const float*)d_in[9];
  float* outp = (float*)d_out;

  char* ws = (char*)d_ws;
  unsigned short* whh_hi = (unsigned short*)ws;
  unsigned short* whh_lo = whh_hi + (size_t)1536 * 512;

  conv_whh<<<3072, 256, 0, stream>>>(W_hh, whh_hi, whh_lo);
  decoder<<<NBLK, 512, 0, stream>>>(enc, ehid, last0, pe, W_ih, b_ih, b_hh,
                                    W_lin, b_lin, whh_hi, whh_lo, outp);
}

// Round 6
// 2698.125 us; speedup vs baseline: 1.3752x; 1.3512x over previous
//
#include <hip/hip_runtime.h>

#define T_IN   24
#define NB     8192
#define HD     512
#define T_OUT  12
#define ROWS   32
#define NBLK   (NB / ROWS)   // 256 blocks = 1 per CU (LDS-pad enforced)

typedef float  f32x4  __attribute__((ext_vector_type(4)));
typedef short  bf16x8 __attribute__((ext_vector_type(8)));

__device__ __forceinline__ unsigned short f2bf(float f){
  unsigned u = __float_as_uint(f);
  u += 0x7fffu + ((u >> 16) & 1u);          // round-to-nearest-even
  return (unsigned short)(u >> 16);
}
__device__ __forceinline__ float bf2f(unsigned short h){
  return __uint_as_float(((unsigned)h) << 16);
}

// XOR-swizzled f32 index into the [ROWS][512] hidden/h2 LDS tile.
// Spreads both the GEMM A-frag pattern (row varies) and the attn pattern
// (row fixed, chunk varies) across bank groups. Bijective per row.
__device__ __forceinline__ int swz(int r, int c){
  int ch  = c >> 3;
  int sch = ch ^ (r & 7) ^ ((ch >> 2) & 3);
  return (r << 9) + (sch << 3) + (c & 7);
}

// ---- W_hh -> bf16 hi/lo split, repacked k-chunk-major: [kt][1536][32] ----
// (GEMM B-frag loads become fully-coalesced 1KB wave reads from L2)
__global__ __launch_bounds__(256) void conv_whh(const float* __restrict__ W,
                                                unsigned short* __restrict__ hi,
                                                unsigned short* __restrict__ lo){
  int idx = blockIdx.x * 256 + threadIdx.x;   // 3072 blocks x 256 = 1536*512
  int j = idx >> 9, k = idx & 511;
  float v = W[idx];
  unsigned short h = f2bf(v);
  int o = ((k >> 5) * 1536 + j) * 32 + (k & 31);
  hi[o] = h;
  lo[o] = f2bf(v - bf2f(h));
}

// ---------------- persistent fused decoder: all 12 steps in one kernel ----------------
// 1024 threads = 16 waves = 4 waves/SIMD (TLP is the round-6 fix; round-5 ran 2/SIMD
// and was latency-dead at 18% HBM). Block owns 32 batch rows. Per step:
// online-softmax attention (f32 logits — precision-critical), split-bf16 MFMA GEMM
// vs repacked W_hh (B streamed from L2), fused GRU gates, output dot.
__global__ __launch_bounds__(1024) void decoder(
    const float* __restrict__ enc,       // f32 [t][b][h]
    const float* __restrict__ ehid,      // f32 [b][h]
    const float* __restrict__ last0,     // f32 [b][4]
    const float* __restrict__ pe,        // f32 [12][4]
    const float* __restrict__ W_ih,      // f32 [1536][8]
    const float* __restrict__ b_ih,      // f32 [1536]
    const float* __restrict__ b_hh,      // f32 [1536]
    const float* __restrict__ Wlin,      // f32 [1024]
    const float* __restrict__ blin,      // f32 [1]
    const unsigned short* __restrict__ Whi,  // bf16 [16][1536][32] k-chunk-major
    const unsigned short* __restrict__ Wlo,
    float* __restrict__ outp)            // f32 [b][12]
{
  // 64KB live + ~17KB tail pad: 2 x 81.5KB > 160KB forces exactly 1 block/CU
  // (eliminates 2-blocks-on-one-CU imbalance; also fixes effective TLP at 4 w/SIMD)
  __shared__ float hid_s[ROWS * HD + 4352];
  __shared__ float last_s[ROWS][4];
  __shared__ float ctxd_s[ROWS];

  const int tid = threadIdx.x;
  const int l   = tid & 63;
  const int w   = tid >> 6;        // wave 0..15
  const int li  = l & 31;          // lane-in-half
  const int hf  = l >> 5;          // half 0/1
  const int rl  = 2 * w + hf;      // attn row 0..31
  const int rg  = blockIdx.x * ROWS + rl;
  const int cb  = li * 4;          // owned cols: cb + 128q, q=0..3
  const int fi  = l & 15;          // MFMA frag row/col
  const int fg  = l >> 4;          // MFMA k-group 0..3

  // ---- init: hidden <- encoder_hid, last <- last_init ----
  {
    const float* hb = ehid + (size_t)rg * HD + cb;
    #pragma unroll
    for (int q = 0; q < 4; q++)
      *(f32x4*)(hid_s + swz(rl, cb + q * 128)) = *(const f32x4*)(hb + q * 128);
    if (li == 0)
      *(float4*)(&last_s[rl][0]) = *(const float4*)(last0 + (size_t)rg * 4);
  }
  __syncthreads();

  const size_t tstride = (size_t)NB * HD;
  const float* ebase = enc + (size_t)rg * HD + cb;

  for (int s = 0; s < T_OUT; s++){
    // ================= A. attention (online softmax over t, f32) =================
    f32x4 hidr[4], ctx[4];
    #pragma unroll
    for (int q = 0; q < 4; q++){
      hidr[q] = *(const f32x4*)(hid_s + swz(rl, cb + q * 128));
      ctx[q]  = (f32x4){0.f, 0.f, 0.f, 0.f};
    }
    float m = -3.0e38f, dsum = 0.f;

    f32x4 eA[4], eB[4];
    auto loadE = [&](f32x4 (&E)[4], int tt){
      const float* pp = ebase + (size_t)tt * tstride;
      #pragma unroll
      for (int q = 0; q < 4; q++) E[q] = *(const f32x4*)(pp + q * 128);
    };
    auto online = [&](const f32x4 (&E)[4]){
      float p = 0.f;
      #pragma unroll
      for (int q = 0; q < 4; q++)
        #pragma unroll
        for (int e = 0; e < 4; e++) p += E[q][e] * hidr[q][e];
      p += __shfl_xor(p, 1); p += __shfl_xor(p, 2); p += __shfl_xor(p, 4);
      p += __shfl_xor(p, 8); p += __shfl_xor(p, 16);     // 32-lane row dot
      float mn = fmaxf(m, p);
      float al = exp2f((m - mn) * 1.44269504f);
      float ph = exp2f((p - mn) * 1.44269504f);
      dsum = dsum * al + ph;
      #pragma unroll
      for (int q = 0; q < 4; q++) ctx[q] = ctx[q] * al + E[q] * ph;
      m = mn;
    };

    loadE(eA, 0); loadE(eB, 1);
    #pragma unroll
    for (int t = 0; t < 22; t += 2){
      online(eA); loadE(eA, t + 2);
      online(eB); loadE(eB, t + 3);
    }
    online(eA); online(eB);

    // normalize context, h2 = hidden + ctx, ctx part of out-dot
    float inv  = 1.f / dsum;
    float cdot = 0.f;
    #pragma unroll
    for (int q = 0; q < 4; q++){
      f32x4 wv = *(const f32x4*)(Wlin + HD + cb + q * 128);
      f32x4 cv = ctx[q] * inv;
      #pragma unroll
      for (int e = 0; e < 4; e++) cdot += cv[e] * wv[e];
      hidr[q] += cv;
    }
    cdot += __shfl_xor(cdot, 1); cdot += __shfl_xor(cdot, 2);
    cdot += __shfl_xor(cdot, 4); cdot += __shfl_xor(cdot, 8);
    cdot += __shfl_xor(cdot, 16);
    if (li == 0) ctxd_s[rl] = cdot + blin[0];

    #pragma unroll
    for (int q = 0; q < 4; q++)
      *(f32x4*)(hid_s + swz(rl, cb + q * 128)) = hidr[q];
    __syncthreads();   // bar1: h2 visible to all

    // ===== C. GEMM k-sweep (gh = h2 @ W_hh^T, split bf16 3-product) =====
    // wave w owns j = w*16 + jh*256 + fi for each gate (all 3 gates in-lane)
    f32x4 acc[3][2][2];   // [gate][jhalf][mtile]
    #pragma unroll
    for (int a = 0; a < 3; a++)
      #pragma unroll
      for (int b = 0; b < 2; b++)
        #pragma unroll
        for (int c = 0; c < 2; c++)
          acc[a][b][c] = (f32x4){0.f, 0.f, 0.f, 0.f};

    #pragma unroll 2
    for (int kt = 0; kt < 16; kt++){
      bf16x8 ah[2], al8[2];
      #pragma unroll
      for (int mt = 0; mt < 2; mt++){
        int o = swz(mt * 16 + fi, kt * 32 + fg * 8);
        f32x4 a0 = *(const f32x4*)(hid_s + o);
        f32x4 a1 = *(const f32x4*)(hid_s + o + 4);
        #pragma unroll
        for (int e = 0; e < 4; e++){
          unsigned short h0 = f2bf(a0[e]);
          unsigned short h1 = f2bf(a1[e]);
          ah[mt][e]      = (short)h0;
          ah[mt][e + 4]  = (short)h1;
          al8[mt][e]     = (short)f2bf(a0[e] - bf2f(h0));
          al8[mt][e + 4] = (short)f2bf(a1[e] - bf2f(h1));
        }
      }
      #pragma unroll
      for (int g = 0; g < 3; g++)
        #pragma unroll
        for (int jh = 0; jh < 2; jh++){
          size_t boff = ((size_t)kt * 1536 + g * 512 + jh * 256 + w * 16 + fi) * 32 + fg * 8;
          bf16x8 bh = *(const bf16x8*)(Whi + boff);
          bf16x8 bl = *(const bf16x8*)(Wlo + boff);
          #pragma unroll
          for (int mt = 0; mt < 2; mt++){
            acc[g][jh][mt] = __builtin_amdgcn_mfma_f32_16x16x32_bf16(ah[mt],  bh, acc[g][jh][mt], 0, 0, 0);
            acc[g][jh][mt] = __builtin_amdgcn_mfma_f32_16x16x32_bf16(al8[mt], bh, acc[g][jh][mt], 0, 0, 0);
            acc[g][jh][mt] = __builtin_amdgcn_mfma_f32_16x16x32_bf16(ah[mt],  bl, acc[g][jh][mt], 0, 0, 0);
          }
        }
    }
    __syncthreads();   // bar2: all h2 reads done before hidden overwrite

    // ================= E. fused GRU epilogue =================
    const float pe0 = pe[s * 4 + 0], pe1 = pe[s * 4 + 1],
                pe2 = pe[s * 4 + 2], pe3 = pe[s * 4 + 3];
    #pragma unroll
    for (int jh = 0; jh < 2; jh++){
      int j = w * 16 + jh * 256 + fi;
      const float* wrp = W_ih + (size_t)j * 8;
      const float* wzp = W_ih + (size_t)(512 + j) * 8;
      const float* wnp = W_ih + (size_t)(1024 + j) * 8;
      float4 wr0 = *(const float4*)wrp, wr1 = *(const float4*)(wrp + 4);
      float4 wz0 = *(const float4*)wzp, wz1 = *(const float4*)(wzp + 4);
      float4 wn0 = *(const float4*)wnp, wn1 = *(const float4*)(wnp + 4);
      float cr = pe0*wr1.x + pe1*wr1.y + pe2*wr1.z + pe3*wr1.w + b_ih[j]        + b_hh[j];
      float cz = pe0*wz1.x + pe1*wz1.y + pe2*wz1.z + pe3*wz1.w + b_ih[512 + j]  + b_hh[512 + j];
      float cn = pe0*wn1.x + pe1*wn1.y + pe2*wn1.z + pe3*wn1.w + b_ih[1024 + j];
      const float bhn = b_hh[1024 + j];
      #pragma unroll
      for (int mt = 0; mt < 2; mt++){
        #pragma unroll
        for (int q = 0; q < 4; q++){
          int row = mt * 16 + fg * 4 + q;       // C-frag row
          float4 x = *(const float4*)(&last_s[row][0]);
          float gr = x.x*wr0.x + x.y*wr0.y + x.z*wr0.z + x.w*wr0.w + cr + acc[0][jh][mt][q];
          float gz = x.x*wz0.x + x.y*wz0.y + x.z*wz0.z + x.w*wz0.w + cz + acc[1][jh][mt][q];
          float gn = x.x*wn0.x + x.y*wn0.y + x.z*wn0.z + x.w*wn0.w + cn;
          float r = 1.f / (1.f + exp2f(-1.44269504f * gr));
          float z = 1.f / (1.f + exp2f(-1.44269504f * gz));
          float nn = gn + r * (acc[2][jh][mt][q] + bhn);
          float th = 1.f - 2.f / (1.f + exp2f(2.88539008f * nn));   // tanh
          int ho = swz(row, j);
          float h = hid_s[ho];                 // h2
          hid_s[ho] = (1.f - z) * th + z * h;  // hidden'
        }
      }
    }
    __syncthreads();   // bar3: hidden' visible

    // ================= G. output dot + last-ring update =================
    float pdot = 0.f;
    #pragma unroll
    for (int q = 0; q < 4; q++){
      f32x4 hv = *(const f32x4*)(hid_s + swz(rl, cb + q * 128));
      f32x4 wv = *(const f32x4*)(Wlin + cb + q * 128);
      #pragma unroll
      for (int e = 0; e < 4; e++) pdot += hv[e] * wv[e];
    }
    pdot += __shfl_xor(pdot, 1); pdot += __shfl_xor(pdot, 2);
    pdot += __shfl_xor(pdot, 4); pdot += __shfl_xor(pdot, 8);
    pdot += __shfl_xor(pdot, 16);
    if (li == 0){
      float val = pdot + ctxd_s[rl];
      outp[(size_t)rg * T_OUT + s] = val;
      float4 old = *(float4*)(&last_s[rl][0]);
      last_s[rl][0] = val;   last_s[rl][1] = old.x;
      last_s[rl][2] = old.y; last_s[rl][3] = old.z;
    }
    // no barrier needed before next step: hid_s/ctxd_s/last_s accesses below bar3
    // are same-thread or separated by next step's bar1/bar2 (round-4/5 analysis).
  }
}

extern "C" void kernel_launch(void* const* d_in, const int* in_sizes, int n_in,
                              void* d_out, int out_size, void* d_ws, size_t ws_size,
                              hipStream_t stream){
  (void)in_sizes; (void)n_in; (void)out_size; (void)ws_size;
  const float* enc   = (const float*)d_in[0];
  const float* ehid  = (const float*)d_in[1];
  const float* last0 = (const float*)d_in[2];
  const float* pe    = (const float*)d_in[3];
  const float* W_ih  = (const float*)d_in[4];
  const float* W_hh  = (const float*)d_in[5];
  const float* b_ih  = (const float*)d_in[6];
  const float* b_hh  = (const float*)d_in[7];
  const float* W_lin = (const float*)d_in[8];
  const float* b_lin = (const float*)d_in[9];
  float* outp = (float*)d_out;

  char* ws = (char*)d_ws;
  unsigned short* whh_hi = (unsigned short*)ws;
  unsigned short* whh_lo = whh_hi + (size_t)1536 * 512;

  conv_whh<<<3072, 256, 0, stream>>>(W_hh, whh_hi, whh_lo);
  decoder<<<NBLK, 1024, 0, stream>>>(enc, ehid, last0, pe, W_ih, b_ih, b_hh,
                                     W_lin, b_lin, whh_hi, whh_lo, outp);
}

// Round 7
// 2320.470 us; speedup vs baseline: 1.5990x; 1.1627x over previous
//
#include <hip/hip_runtime.h>

#define T_IN   24
#define NB     8192
#define HD     512
#define T_OUT  12
#define ROWS   32
#define NBLK   (NB / ROWS)   // 256 blocks = 1 per CU (LDS-pad enforced)

typedef float  f32x4  __attribute__((ext_vector_type(4)));
typedef short  bf16x8 __attribute__((ext_vector_type(8)));

__device__ __forceinline__ unsigned short f2bf(float f){
  unsigned u = __float_as_uint(f);
  u += 0x7fffu + ((u >> 16) & 1u);          // round-to-nearest-even
  return (unsigned short)(u >> 16);
}
__device__ __forceinline__ float bf2f(unsigned short h){
  return __uint_as_float(((unsigned)h) << 16);
}

// XOR-swizzled f32 index into the [ROWS][512] hidden/h2 LDS tile.
// Spreads both the GEMM A-frag pattern (row varies) and the attn pattern
// (row fixed, chunk varies) across bank groups. Bijective per row.
__device__ __forceinline__ int swz(int r, int c){
  int ch  = c >> 3;
  int sch = ch ^ (r & 7) ^ ((ch >> 2) & 3);
  return (r << 9) + (sch << 3) + (c & 7);
}

// ---- W_hh -> bf16 hi/lo split, repacked k-chunk-major: [kt][1536][32] ----
// (GEMM B-frag loads become fully-coalesced 1KB wave reads from L2)
__global__ __launch_bounds__(256) void conv_whh(const float* __restrict__ W,
                                                unsigned short* __restrict__ hi,
                                                unsigned short* __restrict__ lo){
  int idx = blockIdx.x * 256 + threadIdx.x;   // 3072 blocks x 256 = 1536*512
  int j = idx >> 9, k = idx & 511;
  float v = W[idx];
  unsigned short h = f2bf(v);
  int o = ((k >> 5) * 1536 + j) * 32 + (k & 31);
  hi[o] = h;
  lo[o] = f2bf(v - bf2f(h));
}

// ---------------- persistent fused decoder: all 12 steps in one kernel ----------------
// 1024 threads = 16 waves = 4 waves/SIMD. __launch_bounds__(1024, 4) caps the
// allocator at 128 VGPRs (round-6 ran at 64 → enc prefetch couldn't stay resident
// → loads serialized at 1.7 TB/s). 3-deep register ping-pong on the enc stream.
__global__ __launch_bounds__(1024, 4) void decoder(
    const float* __restrict__ enc,       // f32 [t][b][h]
    const float* __restrict__ ehid,      // f32 [b][h]
    const float* __restrict__ last0,     // f32 [b][4]
    const float* __restrict__ pe,        // f32 [12][4]
    const float* __restrict__ W_ih,      // f32 [1536][8]
    const float* __restrict__ b_ih,      // f32 [1536]
    const float* __restrict__ b_hh,      // f32 [1536]
    const float* __restrict__ Wlin,      // f32 [1024]
    const float* __restrict__ blin,      // f32 [1]
    const unsigned short* __restrict__ Whi,  // bf16 [16][1536][32] k-chunk-major
    const unsigned short* __restrict__ Wlo,
    float* __restrict__ outp)            // f32 [b][12]
{
  // 64KB live + ~17KB tail pad: 2 x 81.5KB > 160KB forces exactly 1 block/CU
  __shared__ float hid_s[ROWS * HD + 4352];
  __shared__ float last_s[ROWS][4];
  __shared__ float ctxd_s[ROWS];

  const int tid = threadIdx.x;
  const int l   = tid & 63;
  const int w   = tid >> 6;        // wave 0..15
  const int li  = l & 31;          // lane-in-half
  const int hf  = l >> 5;          // half 0/1
  const int rl  = 2 * w + hf;      // attn row 0..31
  const int rg  = blockIdx.x * ROWS + rl;
  const int cb  = li * 4;          // owned cols: cb + 128q, q=0..3
  const int fi  = l & 15;          // MFMA frag row/col
  const int fg  = l >> 4;          // MFMA k-group 0..3

  // ---- init: hidden <- encoder_hid, last <- last_init ----
  {
    const float* hb = ehid + (size_t)rg * HD + cb;
    #pragma unroll
    for (int q = 0; q < 4; q++)
      *(f32x4*)(hid_s + swz(rl, cb + q * 128)) = *(const f32x4*)(hb + q * 128);
    if (li == 0)
      *(float4*)(&last_s[rl][0]) = *(const float4*)(last0 + (size_t)rg * 4);
  }
  __syncthreads();

  const size_t tstride = (size_t)NB * HD;
  const float* ebase = enc + (size_t)rg * HD + cb;

  for (int s = 0; s < T_OUT; s++){
    // ================= A. attention (online softmax over t, f32) =================
    f32x4 hidr[4], ctx[4];
    #pragma unroll
    for (int q = 0; q < 4; q++){
      hidr[q] = *(const f32x4*)(hid_s + swz(rl, cb + q * 128));
      ctx[q]  = (f32x4){0.f, 0.f, 0.f, 0.f};
    }
    float m = -3.0e38f, dsum = 0.f;

    f32x4 eA[4], eB[4], eC[4];
    auto loadE = [&](f32x4 (&E)[4], int tt){
      const float* pp = ebase + (size_t)tt * tstride;
      #pragma unroll
      for (int q = 0; q < 4; q++) E[q] = *(const f32x4*)(pp + q * 128);
    };
    auto online = [&](const f32x4 (&E)[4]){
      float p = 0.f;
      #pragma unroll
      for (int q = 0; q < 4; q++)
        #pragma unroll
        for (int e = 0; e < 4; e++) p += E[q][e] * hidr[q][e];
      p += __shfl_xor(p, 1); p += __shfl_xor(p, 2); p += __shfl_xor(p, 4);
      p += __shfl_xor(p, 8); p += __shfl_xor(p, 16);     // 32-lane row dot
      float mn = fmaxf(m, p);
      float al = exp2f((m - mn) * 1.44269504f);
      float ph = exp2f((p - mn) * 1.44269504f);
      dsum = dsum * al + ph;
      #pragma unroll
      for (int q = 0; q < 4; q++) ctx[q] = ctx[q] * al + E[q] * ph;
      m = mn;
    };

    // 3-deep ping-pong: online(eX) waits a counted vmcnt while the other two
    // buffers' loads stay in flight (needs the 128-VGPR cap to stay resident)
    loadE(eA, 0); loadE(eB, 1);
    for (int t = 0; t < 21; t += 3){
      loadE(eC, t + 2); online(eA);
      loadE(eA, t + 3); online(eB);
      loadE(eB, t + 4); online(eC);
    }
    loadE(eC, 23); online(eA); online(eB); online(eC);

    // normalize context, h2 = hidden + ctx, ctx part of out-dot
    float inv  = 1.f / dsum;
    float cdot = 0.f;
    #pragma unroll
    for (int q = 0; q < 4; q++){
      f32x4 wv = *(const f32x4*)(Wlin + HD + cb + q * 128);
      f32x4 cv = ctx[q] * inv;
      #pragma unroll
      for (int e = 0; e < 4; e++) cdot += cv[e] * wv[e];
      hidr[q] += cv;
    }
    cdot += __shfl_xor(cdot, 1); cdot += __shfl_xor(cdot, 2);
    cdot += __shfl_xor(cdot, 4); cdot += __shfl_xor(cdot, 8);
    cdot += __shfl_xor(cdot, 16);
    if (li == 0) ctxd_s[rl] = cdot + blin[0];

    #pragma unroll
    for (int q = 0; q < 4; q++)
      *(f32x4*)(hid_s + swz(rl, cb + q * 128)) = hidr[q];
    __syncthreads();   // bar1: h2 visible to all

    // ===== C. GEMM k-sweep (gh = h2 @ W_hh^T, split bf16 3-product) =====
    // wave w owns j = w*16 + jh*256 + fi for each gate (all 3 gates in-lane)
    f32x4 acc[3][2][2];   // [gate][jhalf][mtile]
    #pragma unroll
    for (int a = 0; a < 3; a++)
      #pragma unroll
      for (int b = 0; b < 2; b++)
        #pragma unroll
        for (int c = 0; c < 2; c++)
          acc[a][b][c] = (f32x4){0.f, 0.f, 0.f, 0.f};

    #pragma unroll 2
    for (int kt = 0; kt < 16; kt++){
      bf16x8 ah[2], al8[2];
      #pragma unroll
      for (int mt = 0; mt < 2; mt++){
        int o = swz(mt * 16 + fi, kt * 32 + fg * 8);
        f32x4 a0 = *(const f32x4*)(hid_s + o);
        f32x4 a1 = *(const f32x4*)(hid_s + o + 4);
        #pragma unroll
        for (int e = 0; e < 4; e++){
          unsigned short h0 = f2bf(a0[e]);
          unsigned short h1 = f2bf(a1[e]);
          ah[mt][e]      = (short)h0;
          ah[mt][e + 4]  = (short)h1;
          al8[mt][e]     = (short)f2bf(a0[e] - bf2f(h0));
          al8[mt][e + 4] = (short)f2bf(a1[e] - bf2f(h1));
        }
      }
      #pragma unroll
      for (int g = 0; g < 3; g++)
        #pragma unroll
        for (int jh = 0; jh < 2; jh++){
          size_t boff = ((size_t)kt * 1536 + g * 512 + jh * 256 + w * 16 + fi) * 32 + fg * 8;
          bf16x8 bh = *(const bf16x8*)(Whi + boff);
          bf16x8 bl = *(const bf16x8*)(Wlo + boff);
          #pragma unroll
          for (int mt = 0; mt < 2; mt++){
            acc[g][jh][mt] = __builtin_amdgcn_mfma_f32_16x16x32_bf16(ah[mt],  bh, acc[g][jh][mt], 0, 0, 0);
            acc[g][jh][mt] = __builtin_amdgcn_mfma_f32_16x16x32_bf16(al8[mt], bh, acc[g][jh][mt], 0, 0, 0);
            acc[g][jh][mt] = __builtin_amdgcn_mfma_f32_16x16x32_bf16(ah[mt],  bl, acc[g][jh][mt], 0, 0, 0);
          }
        }
    }
    __syncthreads();   // bar2: all h2 reads done before hidden overwrite

    // ================= E. fused GRU epilogue =================
    const float pe0 = pe[s * 4 + 0], pe1 = pe[s * 4 + 1],
                pe2 = pe[s * 4 + 2], pe3 = pe[s * 4 + 3];
    #pragma unroll
    for (int jh = 0; jh < 2; jh++){
      int j = w * 16 + jh * 256 + fi;
      const float* wrp = W_ih + (size_t)j * 8;
      const float* wzp = W_ih + (size_t)(512 + j) * 8;
      const float* wnp = W_ih + (size_t)(1024 + j) * 8;
      float4 wr0 = *(const float4*)wrp, wr1 = *(const float4*)(wrp + 4);
      float4 wz0 = *(const float4*)wzp, wz1 = *(const float4*)(wzp + 4);
      float4 wn0 = *(const float4*)wnp, wn1 = *(const float4*)(wnp + 4);
      float cr = pe0*wr1.x + pe1*wr1.y + pe2*wr1.z + pe3*wr1.w + b_ih[j]        + b_hh[j];
      float cz = pe0*wz1.x + pe1*wz1.y + pe2*wz1.z + pe3*wz1.w + b_ih[512 + j]  + b_hh[512 + j];
      float cn = pe0*wn1.x + pe1*wn1.y + pe2*wn1.z + pe3*wn1.w + b_ih[1024 + j];
      const float bhn = b_hh[1024 + j];
      #pragma unroll
      for (int mt = 0; mt < 2; mt++){
        #pragma unroll
        for (int q = 0; q < 4; q++){
          int row = mt * 16 + fg * 4 + q;       // C-frag row
          float4 x = *(const float4*)(&last_s[row][0]);
          float gr = x.x*wr0.x + x.y*wr0.y + x.z*wr0.z + x.w*wr0.w + cr + acc[0][jh][mt][q];
          float gz = x.x*wz0.x + x.y*wz0.y + x.z*wz0.z + x.w*wz0.w + cz + acc[1][jh][mt][q];
          float gn = x.x*wn0.x + x.y*wn0.y + x.z*wn0.z + x.w*wn0.w + cn;
          float r = 1.f / (1.f + exp2f(-1.44269504f * gr));
          float z = 1.f / (1.f + exp2f(-1.44269504f * gz));
          float nn = gn + r * (acc[2][jh][mt][q] + bhn);
          float th = 1.f - 2.f / (1.f + exp2f(2.88539008f * nn));   // tanh
          int ho = swz(row, j);
          float h = hid_s[ho];                 // h2
          hid_s[ho] = (1.f - z) * th + z * h;  // hidden'
        }
      }
    }
    __syncthreads();   // bar3: hidden' visible

    // ================= G. output dot + last-ring update =================
    float pdot = 0.f;
    #pragma unroll
    for (int q = 0; q < 4; q++){
      f32x4 hv = *(const f32x4*)(hid_s + swz(rl, cb + q * 128));
      f32x4 wv = *(const f32x4*)(Wlin + cb + q * 128);
      #pragma unroll
      for (int e = 0; e < 4; e++) pdot += hv[e] * wv[e];
    }
    pdot += __shfl_xor(pdot, 1); pdot += __shfl_xor(pdot, 2);
    pdot += __shfl_xor(pdot, 4); pdot += __shfl_xor(pdot, 8);
    pdot += __shfl_xor(pdot, 16);
    if (li == 0){
      float val = pdot + ctxd_s[rl];
      outp[(size_t)rg * T_OUT + s] = val;
      float4 old = *(float4*)(&last_s[rl][0]);
      last_s[rl][0] = val;   last_s[rl][1] = old.x;
      last_s[rl][2] = old.y; last_s[rl][3] = old.z;
    }
    // no barrier needed before next step: hid_s/ctxd_s/last_s accesses below bar3
    // are same-thread or separated by next step's bar1/bar2 (round-4/5 analysis).
  }
}

extern "C" void kernel_launch(void* const* d_in, const int* in_sizes, int n_in,
                              void* d_out, int out_size, void* d_ws, size_t ws_size,
                              hipStream_t stream){
  (void)in_sizes; (void)n_in; (void)out_size; (void)ws_size;
  const float* enc   = (const float*)d_in[0];
  const float* ehid  = (const float*)d_in[1];
  const float* last0 = (const float*)d_in[2];
  const float* pe    = (const float*)d_in[3];
  const float* W_ih  = (const float*)d_in[4];
  const float* W_hh  = (const float*)d_in[5];
  const float* b_ih  = (const float*)d_in[6];
  const float* b_hh  = (const float*)d_in[7];
  const float* W_lin = (const float*)d_in[8];
  const float* b_lin = (const float*)d_in[9];
  float* outp = (float*)d_out;

  char* ws = (char*)d_ws;
  unsigned short* whh_hi = (unsigned short*)ws;
  unsigned short* whh_lo = whh_hi + (size_t)1536 * 512;

  conv_whh<<<3072, 256, 0, stream>>>(W_hh, whh_hi, whh_lo);
  decoder<<<NBLK, 1024, 0, stream>>>(enc, ehid, last0, pe, W_ih, b_ih, b_hh,
                                     W_lin, b_lin, whh_hi, whh_lo, outp);
}